// Round 9
// baseline (325.225 us; speedup 1.0000x reference)
//
#include <hip/hip_runtime.h>
#include <hip/hip_fp16.h>
#include <math.h>

// Problem constants
#define BB   8
#define HW   4096
#define BHW  32768
#define DIM  256
#define CR   64
#define GC   32
#define NHD  4
#define HC   16
#define NTAP 9
#define NCLS 80

// workspace layout (float offsets)
#define OFF_TMPG 0u          // k5 intermediate [256][B*HW] fp32     8,388,608
                             //   (overlays QP/QT/KT region — dead after k4)
#define OFF_QP   0u          // q planar   [B][64][H][W] fp32       2,097,152
#define OFF_QT   2097152u    // q pix-major[B*HW][64] fp16          1,048,576 (floats of space)
#define OFF_KT   4194304u    // KV fp16 [BG][HW][2 sub][k16|v16]    2,097,152 (floats of space)
// --- region 8,388,608+ : prep-weight area (no longer clobbered; t now in LDS) ---
#define OFF_WQT  8388608u    // wqkv^T * g1  [256][192]             49,152
#define OFF_AB   8437760u    // A[192], B[192]                      384
// ------------------------------------------------------------------------
#define OFF_OFFB 10485760u   // off planar [BG][18][H][W]           1,179,648
#define OFF_AOT  11665408u   // attn out   [64][B*HW] planar fp32   2,097,152
#define OFF_WPT  13762560u   // wproj^T [64][256]                   16,384
#define OFF_WCT  13778944u   // wcls^T  [256][80]                   20,480
#define OFF_WFT  13799424u   // woff^T  [9][32][18]                 5,184

// ---------------- k0: all weight prep (transposes + LN-fold vectors) ----------------
// grid 257: blocks 0..255 = transposes (c = blk); block 256 = AB vectors + woff^T
__global__ __launch_bounds__(256) void k0_prep(
    const float* __restrict__ wqkv, const float* __restrict__ g1,
    const float* __restrict__ b1, const float* __restrict__ woff,
    const float* __restrict__ wproj, const float* __restrict__ wcls,
    float* __restrict__ ws)
{
    const int t = threadIdx.x;
    const int blk = blockIdx.x;
    if (blk < 256) {
        const int c = blk;
        if (t < 192) ws[OFF_WQT + c * 192 + t] = wqkv[t * 256 + c] * g1[c];
        if (c < 64)  ws[OFF_WPT + c * 256 + t] = wproj[t * 64 + c];
        if (t < 80)  ws[OFF_WCT + c * 80 + t]  = wcls[t * 256 + c];
    } else {
        if (t < 192) {
            float a = 0.f, bb = 0.f;
            for (int c = 0; c < 256; ++c) {
                float w = wqkv[t * 256 + c];
                a += w * g1[c]; bb += w * b1[c];
            }
            ws[OFF_AB + t] = a;
            ws[OFF_AB + 192 + t] = bb;
            for (int pair = t; pair < 288; pair += 192) {
                int wo = pair >> 5, ic = pair & 31;
                for (int o = 0; o < 18; ++o)
                    ws[OFF_WFT + (wo * 32 + ic) * 18 + o] = woff[(o * 32 + ic) * 9 + wo];
            }
        }
    }
}

// ------ k1: QKV GEMM, LN stats computed inline (k0c fused), fp16 q/KV epilogue ------
// grid 1024: mhalf=blk>>9 (96 outputs each), (b,row)=blk&511. block 256.
__global__ __launch_bounds__(256) void k1_gemm(
    const float* __restrict__ x, float* __restrict__ ws)
{
    __shared__ float smem[8192];     // 2x 16KB staging; reused as 64x97 transpose tile
    const int t = threadIdx.x;
    const int mhalf = blockIdx.x >> 9;
    const int rb = blockIdx.x & 511;
    const int b = rb >> 6, row = rb & 63;
    const int p = t & 63;
    const int og = __builtin_amdgcn_readfirstlane(t >> 6);
    const int obase = mhalf * 96 + og * 24;
    const float* wqT = ws + OFF_WQT;
    const float* AB  = ws + OFF_AB;
    const size_t xbase = (size_t)b * DIM * HW + row * 64;

    float acc[24];
    #pragma unroll
    for (int j = 0; j < 24; ++j) acc[j] = 0.f;
    float s = 0.f, ss = 0.f;        // inline LN stats for pixel (row,p)

    #pragma unroll
    for (int j = 0; j < 4; ++j) {
        int idx4 = t + j * 256;
        int c = idx4 >> 4, p4 = (idx4 & 15) << 2;
        float4 v = *(const float4*)&x[xbase + (size_t)c * HW + p4];
        *(float4*)&smem[c * 64 + p4] = v;
    }
    __syncthreads();

    for (int kt = 0; kt < 4; ++kt) {
        const int cur = kt & 1;
        float4 pf[4];
        if (kt < 3) {
            #pragma unroll
            for (int j = 0; j < 4; ++j) {
                int idx4 = t + j * 256;
                int c = idx4 >> 4, p4 = (idx4 & 15) << 2;
                pf[j] = *(const float4*)&x[xbase + (size_t)((kt + 1) * 64 + c) * HW + p4];
            }
        }
        const float* wb = wqT + (size_t)kt * 64 * 192 + obase;
        #pragma unroll 8
        for (int c = 0; c < 64; ++c) {
            float xv = smem[cur * 4096 + c * 64 + p];
            s += xv; ss += xv * xv;
            #pragma unroll
            for (int j = 0; j < 24; ++j)
                acc[j] += wb[c * 192 + j] * xv;
        }
        if (kt < 3) {
            #pragma unroll
            for (int j = 0; j < 4; ++j) {
                int idx4 = t + j * 256;
                int c = idx4 >> 4, p4 = (idx4 & 15) << 2;
                *(float4*)&smem[(cur ^ 1) * 4096 + c * 64 + p4] = pf[j];
            }
            __syncthreads();
        }
    }
    __syncthreads();

    const float m = s * (1.f / 256.f);
    const float var = ss * (1.f / 256.f) - m * m;
    const float rsv = rsqrtf(var + 1e-5f);
    #pragma unroll
    for (int j = 0; j < 24; ++j) {
        int o = obase + j;
        smem[p * 97 + og * 24 + j] = rsv * (acc[j] - m * AB[o]) + AB[192 + o];
    }
    __syncthreads();

    float*  qp  = ws + OFF_QP;
    __half* qth = (__half*)(ws + OFF_QT);
    __half* kvh = (__half*)(ws + OFF_KT);
    const int colrow = row * 64;
    if (mhalf == 0) {
        // q planar fp32 (k23 input)
        #pragma unroll
        for (int it = 0; it < 16; ++it) {
            int idx = it * 256 + t;
            int o = idx >> 6, px = idx & 63;
            qp[(size_t)(b * 64 + o) * HW + colrow + px] = smem[px * 97 + o];
        }
        // q pixel-major fp16 (k4 input)
        #pragma unroll
        for (int it = 0; it < 16; ++it) {
            int idx = it * 256 + t;
            int px = idx >> 6, o = idx & 63;
            qth[(size_t)(b * HW + colrow + px) * 64 + o] = __float2half(smem[px * 97 + o]);
        }
        // k of bg=2b (tile cols 64..95)
        #pragma unroll
        for (int it = 0; it < 8; ++it) {
            int idx = it * 256 + t;
            int px = idx >> 5, ch32 = idx & 31;
            int sB = ch32 >> 4, ch = ch32 & 15;
            kvh[(size_t)((2 * b) * HW + colrow + px) * 64 + sB * 32 + ch]
                = __float2half(smem[px * 97 + 64 + ch32]);
        }
    } else {
        // k of bg=2b+1 (cols 0..31)
        #pragma unroll
        for (int it = 0; it < 8; ++it) {
            int idx = it * 256 + t;
            int px = idx >> 5, ch32 = idx & 31;
            int sB = ch32 >> 4, ch = ch32 & 15;
            kvh[(size_t)((2 * b + 1) * HW + colrow + px) * 64 + sB * 32 + ch]
                = __float2half(smem[px * 97 + ch32]);
        }
        // v of bg=2b (cols 32..63)
        #pragma unroll
        for (int it = 0; it < 8; ++it) {
            int idx = it * 256 + t;
            int px = idx >> 5, ch32 = idx & 31;
            int sB = ch32 >> 4, ch = ch32 & 15;
            kvh[(size_t)((2 * b) * HW + colrow + px) * 64 + sB * 32 + 16 + ch]
                = __float2half(smem[px * 97 + 32 + ch32]);
        }
        // v of bg=2b+1 (cols 64..95)
        #pragma unroll
        for (int it = 0; it < 8; ++it) {
            int idx = it * 256 + t;
            int px = idx >> 5, ch32 = idx & 31;
            int sB = ch32 >> 4, ch = ch32 & 15;
            kvh[(size_t)((2 * b + 1) * HW + colrow + px) * 64 + sB * 32 + 16 + ch]
                = __float2half(smem[px * 97 + 64 + ch32]);
        }
    }
}

// ---- k23: fused offset branch: dwconv+LN+GELU (3 rows, LDS) -> conv32->18 ----
// grid 1024 (bg*64+row), block 256.
// Phase 1: threads 0..191 = (prow 0..2, px 0..63); each computes 32 channels of t
//          for row (row+prow-1) into LDS tile tl (zero for out-of-range rows).
// Phase 2: wave w owns outputs [w*5, ...) (5,5,4,4); thread = pixel.
__global__ __launch_bounds__(256) void k23_off(
    const float* __restrict__ wdw, const float* __restrict__ g2, const float* __restrict__ b2,
    const float* __restrict__ boff, const float* __restrict__ off_in,
    float* __restrict__ ws)
{
    __shared__ float tl[3][32][64];   // 24 KB
    const int t = threadIdx.x;
    const int bg = blockIdx.x >> 6, row = blockIdx.x & 63;
    const int b = bg >> 1, g = bg & 1;
    const float* qp = ws + OFF_QP;

    if (t < 192) {
        const int pr = t >> 6;        // wave-uniform
        const int p  = t & 63;
        const int y  = row + pr - 1;
        if ((unsigned)y < 64u) {
            float vals[32];
            float s = 0.f, sq = 0.f;
            #pragma unroll
            for (int ch = 0; ch < 32; ++ch) {
                const float* plane = qp + (size_t)(b * 64 + g * 32 + ch) * HW;
                float a = 0.f;
                #pragma unroll
                for (int dy = 0; dy < 3; ++dy) {
                    int yy = y + dy - 1;
                    if ((unsigned)yy >= 64u) continue;   // wave-uniform branch
                    #pragma unroll
                    for (int dx = 0; dx < 3; ++dx) {
                        int xx = p + dx - 1;
                        bool vld = (unsigned)xx < 64u;
                        float q = plane[yy * 64 + (vld ? xx : 0)];
                        a += (vld ? q : 0.f) * wdw[ch * 9 + dy * 3 + dx];
                    }
                }
                vals[ch] = a; s += a; sq += a * a;
            }
            float m = s * (1.f / 32.f);
            float var = sq * (1.f / 32.f) - m * m;
            float rv = rsqrtf(var + 1e-5f);
            #pragma unroll
            for (int ch = 0; ch < 32; ++ch) {
                float u = (vals[ch] - m) * rv * g2[ch] + b2[ch];
                tl[pr][ch][p] = 0.5f * u * (1.f + erff(u * 0.70710678118654752f));
            }
        } else {
            #pragma unroll
            for (int ch = 0; ch < 32; ++ch) tl[pr][ch][p] = 0.f;
        }
    }
    __syncthreads();

    const int p  = t & 63;
    const int wv = __builtin_amdgcn_readfirstlane(t >> 6);
    const int o0 = (wv < 2) ? wv * 5 : 10 + (wv - 2) * 4;
    const int no = (wv < 2) ? 5 : 4;
    const float* wfT = ws + OFF_WFT;
    float acc[5];
    #pragma unroll
    for (int i = 0; i < 5; ++i) acc[i] = (i < no) ? boff[o0 + i] : 0.f;
    #pragma unroll
    for (int pr = 0; pr < 3; ++pr) {
        #pragma unroll
        for (int dx = 0; dx < 3; ++dx) {
            int xx = p + dx - 1;
            bool vld = (unsigned)xx < 64u;
            int xc = vld ? xx : 0;
            const int wo = pr * 3 + dx;
            #pragma unroll 8
            for (int ic = 0; ic < 32; ++ic) {
                float tv = tl[pr][ic][xc];
                tv = vld ? tv : 0.f;
                const float* wrow = wfT + (wo * 32 + ic) * 18 + o0;
                #pragma unroll
                for (int i = 0; i < 5; ++i)
                    if (i < no) acc[i] += tv * wrow[i];
            }
        }
    }
    float* ob = ws + OFF_OFFB;
    #pragma unroll
    for (int i = 0; i < 5; ++i) {
        if (i < no) {
            int o = o0 + i;
            float v = tanhf(acc[i]) * 5.0f + off_in[(size_t)(b * 18 + o) * HW + row * 64 + p];
            ob[(size_t)(bg * 18 + o) * HW + row * 64 + p] = v;
        }
    }
}

// ---- k4: deformable gather + softmax attn, fp16 KV, one wave = one group ----
__global__ __launch_bounds__(256, 2) void k4_attn(
    const float* __restrict__ rpb, float* __restrict__ ws)
{
    __shared__ float rpb_l[NHD * NTAP * HC]; // 576 floats
    for (int i = threadIdx.x; i < NHD * NTAP * HC; i += 256) rpb_l[i] = rpb[i];
    __syncthreads();

    const int t = threadIdx.x;
    const int wave = __builtin_amdgcn_readfirstlane(t >> 6);
    const int g = wave & 1, pxh = wave >> 1;
    const int lane = t & 63;
    const int pxl = lane & 7;
    const int prt = lane >> 3;
    const int s    = prt >> 2;
    const int half = (prt >> 1) & 1;
    const int j    = prt & 1;
    const int b = blockIdx.x & 7;
    const int chunk = blockIdx.x >> 3;          // 0..255
    const int hw = chunk * 16 + pxh * 8 + pxl;
    const int pix = b * HW + hw;
    const int bg = b * 2 + g;
    const int head = g * 2 + s;

    const __half* qth = (const __half*)(ws + OFF_QT);
    const __half* kvh = (const __half*)(ws + OFF_KT);
    const float*  ob  = ws + OFF_OFFB;

    union F4H { float4 f; __half2 h[4]; };
    F4H qld;
    qld.f = *(const float4*)&qth[(size_t)pix * 64 + g * 32 + s * 16 + j * 8];
    const float qs = half ? 0.0f : 0.25f;
    float qv[8];
    #pragma unroll
    for (int i = 0; i < 4; ++i) {
        float2 q2 = __half22float2(qld.h[i]);
        qv[2 * i] = q2.x * qs; qv[2 * i + 1] = q2.y * qs;
    }

    const float4* rb4 = (const float4*)(rpb_l + head * (NTAP * HC) + j * 8);
    const __half* kvp = kvh + (size_t)(bg * HW) * 64 + prt * 8;

    __half2 av[NTAP][4];
    float logit[NTAP];

    #pragma unroll
    for (int n = 0; n < NTAP; ++n) {
        float r = ob[(size_t)(bg * 18 + 2 * n) * HW + hw];
        float c = ob[(size_t)(bg * 18 + 2 * n + 1) * HW + hw];
        float y0f = floorf(r), x0f = floorf(c);
        float fy = r - y0f, fx = c - x0f;
        int iy0 = (int)y0f, ix0 = (int)x0f;
        float wts[4] = { (1.f - fx) * (1.f - fy), fx * (1.f - fy),
                         (1.f - fx) * fy,         fx * fy };
        __half2 acc0 = __float2half2_rn(0.f), acc1 = acc0, acc2 = acc0, acc3 = acc0;
        #pragma unroll
        for (int corner = 0; corner < 4; ++corner) {
            int cxx = ix0 + (corner & 1);
            int cyy = iy0 + (corner >> 1);
            bool vld = ((unsigned)cxx < 64u) && ((unsigned)cyy < 64u);
            float w = vld ? wts[corner] : 0.f;
            int cxc = min(max(cxx, 0), 63);
            int cyc = min(max(cyy, 0), 63);
            F4H kv;
            kv.f = *(const float4*)&kvp[(size_t)(cyc * 64 + cxc) * 64];
            __half2 w2 = __float2half2_rn(w);
            acc0 = __hfma2(kv.h[0], w2, acc0);
            acc1 = __hfma2(kv.h[1], w2, acc1);
            acc2 = __hfma2(kv.h[2], w2, acc2);
            acc3 = __hfma2(kv.h[3], w2, acc3);
        }
        av[n][0] = acc0; av[n][1] = acc1; av[n][2] = acc2; av[n][3] = acc3;
        float4 r0 = rb4[n * 4], r1 = rb4[n * 4 + 1];
        float2 a0 = __half22float2(acc0), a1 = __half22float2(acc1);
        float2 a2 = __half22float2(acc2), a3 = __half22float2(acc3);
        float part = qv[0] * (a0.x + r0.x) + qv[1] * (a0.y + r0.y)
                   + qv[2] * (a1.x + r0.z) + qv[3] * (a1.y + r0.w)
                   + qv[4] * (a2.x + r1.x) + qv[5] * (a2.y + r1.y)
                   + qv[6] * (a3.x + r1.z) + qv[7] * (a3.y + r1.w);
        part += __shfl_xor(part, 8, 64);
        part += __shfl_xor(part, 16, 64);
        logit[n] = part;
    }

    float m = logit[0];
    #pragma unroll
    for (int n = 1; n < NTAP; ++n) m = fmaxf(m, logit[n]);
    float l = 0.f;
    #pragma unroll
    for (int n = 0; n < NTAP; ++n) { logit[n] = __expf(logit[n] - m); l += logit[n]; }
    const float inv = 1.f / l;

    __half2 o0 = __float2half2_rn(0.f), o1 = o0, o2 = o0, o3 = o0;
    #pragma unroll
    for (int n = 0; n < NTAP; ++n) {
        __half2 p2 = __float2half2_rn(logit[n]);
        o0 = __hfma2(av[n][0], p2, o0);
        o1 = __hfma2(av[n][1], p2, o1);
        o2 = __hfma2(av[n][2], p2, o2);
        o3 = __hfma2(av[n][3], p2, o3);
    }
    if (half) {   // v-lanes write
        float* ao = ws + OFF_AOT;
        const int cb = head * 16 + j * 8;
        float2 f0 = __half22float2(o0), f1 = __half22float2(o1);
        float2 f2 = __half22float2(o2), f3 = __half22float2(o3);
        ao[(size_t)(cb + 0) * BHW + pix] = f0.x * inv;
        ao[(size_t)(cb + 1) * BHW + pix] = f0.y * inv;
        ao[(size_t)(cb + 2) * BHW + pix] = f1.x * inv;
        ao[(size_t)(cb + 3) * BHW + pix] = f1.y * inv;
        ao[(size_t)(cb + 4) * BHW + pix] = f2.x * inv;
        ao[(size_t)(cb + 5) * BHW + pix] = f2.y * inv;
        ao[(size_t)(cb + 6) * BHW + pix] = f3.x * inv;
        ao[(size_t)(cb + 7) * BHW + pix] = f3.y * inv;
    }
}

// ------ k5a: proj(64->256) + bias + residual -> tmpG planar [256][B*HW] ------
__global__ __launch_bounds__(256) void k5a_proj(
    const float* __restrict__ x, const float* __restrict__ bproj,
    float* __restrict__ ws)
{
    const int t = threadIdx.x;
    const int mhalf = blockIdx.x >> 9;
    const int rb = blockIdx.x & 511;
    const int b = rb >> 6, row = rb & 63;
    const int p = t & 63;
    const int wv = __builtin_amdgcn_readfirstlane(t >> 6);
    const int cb = mhalf * 128 + wv * 32;
    const float* ao  = ws + OFF_AOT;
    const float* wpT = ws + OFF_WPT;
    float* tmpG = ws + OFF_TMPG;
    const int pixcol = row * 64 + p;
    const size_t aob = (size_t)b * HW + pixcol;

    float acc[32];
    #pragma unroll
    for (int j = 0; j < 32; ++j) acc[j] = 0.f;
    #pragma unroll 4
    for (int cr = 0; cr < 64; ++cr) {
        float av = ao[(size_t)cr * BHW + aob];
        const float* wrow = wpT + cr * 256 + cb;
        #pragma unroll
        for (int j = 0; j < 32; ++j)
            acc[j] += av * wrow[j];
    }
    #pragma unroll
    for (int j = 0; j < 32; ++j) {
        int c = cb + j;
        tmpG[(size_t)c * BHW + aob] = acc[j] + bproj[c] + x[(size_t)(b * DIM + c) * HW + pixcol];
    }
}

// ------ k5b: cls head (256->80) from tmpG ------
__global__ __launch_bounds__(256) void k5b_cls(
    const float* __restrict__ bcls, const float* __restrict__ wsr, float* __restrict__ out)
{
    const int t = threadIdx.x;
    const int ochalf = blockIdx.x >> 9;
    const int rb = blockIdx.x & 511;
    const int b = rb >> 6, row = rb & 63;
    const int p = t & 63;
    const int wv = __builtin_amdgcn_readfirstlane(t >> 6);
    const int oc0 = ochalf * 40 + wv * 10;
    const float* tmpG = wsr + OFF_TMPG;
    const float* wcT  = wsr + OFF_WCT;
    const int pixcol = row * 64 + p;
    const size_t pixb = (size_t)b * HW + pixcol;

    float acc2[10];
    #pragma unroll
    for (int j = 0; j < 10; ++j) acc2[j] = bcls[oc0 + j];
    #pragma unroll 4
    for (int c = 0; c < 256; ++c) {
        float tv = tmpG[(size_t)c * BHW + pixb];
        const float* wrow = wcT + c * 80 + oc0;
        #pragma unroll
        for (int j = 0; j < 10; ++j)
            acc2[j] += tv * wrow[j];
    }
    #pragma unroll
    for (int j = 0; j < 10; ++j)
        out[(size_t)(b * NCLS + oc0 + j) * HW + pixcol] = acc2[j];
}

extern "C" void kernel_launch(void* const* d_in, const int* in_sizes, int n_in,
                              void* d_out, int out_size, void* d_ws, size_t ws_size,
                              hipStream_t stream)
{
    const float* x     = (const float*)d_in[0];
    const float* off   = (const float*)d_in[1];
    const float* g1    = (const float*)d_in[2];
    const float* b1    = (const float*)d_in[3];
    const float* wqkv  = (const float*)d_in[4];
    const float* wdw   = (const float*)d_in[5];
    const float* g2    = (const float*)d_in[6];
    const float* b2    = (const float*)d_in[7];
    const float* woff  = (const float*)d_in[8];
    const float* boff  = (const float*)d_in[9];
    const float* rpb   = (const float*)d_in[10];
    const float* wproj = (const float*)d_in[11];
    const float* bproj = (const float*)d_in[12];
    const float* wcls  = (const float*)d_in[13];
    const float* bcls  = (const float*)d_in[14];
    float* ws  = (float*)d_ws;
    float* out = (float*)d_out;

    hipLaunchKernelGGL(k0_prep,  dim3(257),  dim3(256), 0, stream, wqkv, g1, b1, woff, wproj, wcls, ws);
    hipLaunchKernelGGL(k1_gemm,  dim3(1024), dim3(256), 0, stream, x, ws);
    hipLaunchKernelGGL(k23_off,  dim3(1024), dim3(256), 0, stream, wdw, g2, b2, boff, off, ws);
    hipLaunchKernelGGL(k4_attn,  dim3(2048), dim3(256), 0, stream, rpb, ws);
    hipLaunchKernelGGL(k5a_proj, dim3(1024), dim3(256), 0, stream, x, bproj, ws);
    hipLaunchKernelGGL(k5b_cls,  dim3(1024), dim3(256), 0, stream, bcls, ws, out);
}

// Round 10
// 264.449 us; speedup vs baseline: 1.2298x; 1.2298x over previous
//
#include <hip/hip_runtime.h>
#include <hip/hip_fp16.h>
#include <math.h>

// Problem constants
#define BB   8
#define HW   4096
#define BHW  32768
#define DIM  256
#define CR   64
#define GC   32
#define NHD  4
#define HC   16
#define NTAP 9
#define NCLS 80

// workspace layout (float offsets)
#define OFF_TMPG 0u          // k5 intermediate [256][B*HW] fp32     8,388,608
                             //   (overlays QP/QT/KT region — dead after k4)
#define OFF_QP   0u          // q planar   [B][64][H][W] fp32       2,097,152
#define OFF_QT   2097152u    // q pix-major[B*HW][64] fp16          1,048,576 (floats of space)
#define OFF_KT   4194304u    // KV fp16 [BG][HW][2 sub][k16|v16]    2,097,152 (floats of space)
#define OFF_T    8388608u    // t planar   [BG][32][H][W]           2,097,152
// --- overlap region: inside OFF_T's span; k0 writes these each call, k1 reads
//     them, then k2 clobbers with T (k1 already done) ---
#define OFF_WQT  8388608u    // wqkv^T * g1  [256][192]             49,152
#define OFF_AB   8437760u    // A[192], B[192]                      384
// ------------------------------------------------------------------------
#define OFF_OFFB 10485760u   // off planar [BG][18][H][W]           1,179,648
#define OFF_AOT  11665408u   // attn out   [64][B*HW] planar fp32   2,097,152
#define OFF_WPT  13762560u   // wproj^T [64][256]                   16,384
#define OFF_WCT  13778944u   // wcls^T  [256][80]                   20,480
#define OFF_WFT  13799424u   // woff^T  [9][32][18]                 5,184

// ---------------- k0: all weight prep (transposes + LN-fold vectors) ----------------
// grid 257: blocks 0..255 = transposes (c = blk); block 256 = AB vectors + woff^T
__global__ __launch_bounds__(256) void k0_prep(
    const float* __restrict__ wqkv, const float* __restrict__ g1,
    const float* __restrict__ b1, const float* __restrict__ woff,
    const float* __restrict__ wproj, const float* __restrict__ wcls,
    float* __restrict__ ws)
{
    const int t = threadIdx.x;
    const int blk = blockIdx.x;
    if (blk < 256) {
        const int c = blk;
        if (t < 192) ws[OFF_WQT + c * 192 + t] = wqkv[t * 256 + c] * g1[c];
        if (c < 64)  ws[OFF_WPT + c * 256 + t] = wproj[t * 64 + c];
        if (t < 80)  ws[OFF_WCT + c * 80 + t]  = wcls[t * 256 + c];
    } else {
        if (t < 192) {
            float a = 0.f, bb = 0.f;
            for (int c = 0; c < 256; ++c) {
                float w = wqkv[t * 256 + c];
                a += w * g1[c]; bb += w * b1[c];
            }
            ws[OFF_AB + t] = a;
            ws[OFF_AB + 192 + t] = bb;
            for (int pair = t; pair < 288; pair += 192) {
                int wo = pair >> 5, ic = pair & 31;
                for (int o = 0; o < 18; ++o)
                    ws[OFF_WFT + (wo * 32 + ic) * 18 + o] = woff[(o * 32 + ic) * 9 + wo];
            }
        }
    }
}

// ------ k1: QKV GEMM, LN stats computed inline, fp16 q/KV epilogue ------
// grid 1024: mhalf=blk>>9 (96 outputs each), (b,row)=blk&511. block 256.
__global__ __launch_bounds__(256) void k1_gemm(
    const float* __restrict__ x, float* __restrict__ ws)
{
    __shared__ float smem[8192];     // 2x 16KB staging; reused as 64x97 transpose tile
    const int t = threadIdx.x;
    const int mhalf = blockIdx.x >> 9;
    const int rb = blockIdx.x & 511;
    const int b = rb >> 6, row = rb & 63;
    const int p = t & 63;
    const int og = __builtin_amdgcn_readfirstlane(t >> 6);
    const int obase = mhalf * 96 + og * 24;
    const float* wqT = ws + OFF_WQT;
    const float* AB  = ws + OFF_AB;
    const size_t xbase = (size_t)b * DIM * HW + row * 64;

    float acc[24];
    #pragma unroll
    for (int j = 0; j < 24; ++j) acc[j] = 0.f;
    float s = 0.f, ss = 0.f;        // inline LN stats for pixel (row,p)

    #pragma unroll
    for (int j = 0; j < 4; ++j) {
        int idx4 = t + j * 256;
        int c = idx4 >> 4, p4 = (idx4 & 15) << 2;
        float4 v = *(const float4*)&x[xbase + (size_t)c * HW + p4];
        *(float4*)&smem[c * 64 + p4] = v;
    }
    __syncthreads();

    for (int kt = 0; kt < 4; ++kt) {
        const int cur = kt & 1;
        float4 pf[4];
        if (kt < 3) {
            #pragma unroll
            for (int j = 0; j < 4; ++j) {
                int idx4 = t + j * 256;
                int c = idx4 >> 4, p4 = (idx4 & 15) << 2;
                pf[j] = *(const float4*)&x[xbase + (size_t)((kt + 1) * 64 + c) * HW + p4];
            }
        }
        const float* wb = wqT + (size_t)kt * 64 * 192 + obase;
        #pragma unroll 8
        for (int c = 0; c < 64; ++c) {
            float xv = smem[cur * 4096 + c * 64 + p];
            s += xv; ss += xv * xv;
            #pragma unroll
            for (int j = 0; j < 24; ++j)
                acc[j] += wb[c * 192 + j] * xv;
        }
        if (kt < 3) {
            #pragma unroll
            for (int j = 0; j < 4; ++j) {
                int idx4 = t + j * 256;
                int c = idx4 >> 4, p4 = (idx4 & 15) << 2;
                *(float4*)&smem[(cur ^ 1) * 4096 + c * 64 + p4] = pf[j];
            }
            __syncthreads();
        }
    }
    __syncthreads();

    const float m = s * (1.f / 256.f);
    const float var = ss * (1.f / 256.f) - m * m;
    const float rsv = rsqrtf(var + 1e-5f);
    #pragma unroll
    for (int j = 0; j < 24; ++j) {
        int o = obase + j;
        smem[p * 97 + og * 24 + j] = rsv * (acc[j] - m * AB[o]) + AB[192 + o];
    }
    __syncthreads();

    float*  qp  = ws + OFF_QP;
    __half* qth = (__half*)(ws + OFF_QT);
    __half* kvh = (__half*)(ws + OFF_KT);
    const int colrow = row * 64;
    if (mhalf == 0) {
        // q planar fp32 (k2 input)
        #pragma unroll
        for (int it = 0; it < 16; ++it) {
            int idx = it * 256 + t;
            int o = idx >> 6, px = idx & 63;
            qp[(size_t)(b * 64 + o) * HW + colrow + px] = smem[px * 97 + o];
        }
        // q pixel-major fp16 (k4 input)
        #pragma unroll
        for (int it = 0; it < 16; ++it) {
            int idx = it * 256 + t;
            int px = idx >> 6, o = idx & 63;
            qth[(size_t)(b * HW + colrow + px) * 64 + o] = __float2half(smem[px * 97 + o]);
        }
        // k of bg=2b (tile cols 64..95)
        #pragma unroll
        for (int it = 0; it < 8; ++it) {
            int idx = it * 256 + t;
            int px = idx >> 5, ch32 = idx & 31;
            int sB = ch32 >> 4, ch = ch32 & 15;
            kvh[(size_t)((2 * b) * HW + colrow + px) * 64 + sB * 32 + ch]
                = __float2half(smem[px * 97 + 64 + ch32]);
        }
    } else {
        // k of bg=2b+1 (cols 0..31)
        #pragma unroll
        for (int it = 0; it < 8; ++it) {
            int idx = it * 256 + t;
            int px = idx >> 5, ch32 = idx & 31;
            int sB = ch32 >> 4, ch = ch32 & 15;
            kvh[(size_t)((2 * b + 1) * HW + colrow + px) * 64 + sB * 32 + ch]
                = __float2half(smem[px * 97 + ch32]);
        }
        // v of bg=2b (cols 32..63)
        #pragma unroll
        for (int it = 0; it < 8; ++it) {
            int idx = it * 256 + t;
            int px = idx >> 5, ch32 = idx & 31;
            int sB = ch32 >> 4, ch = ch32 & 15;
            kvh[(size_t)((2 * b) * HW + colrow + px) * 64 + sB * 32 + 16 + ch]
                = __float2half(smem[px * 97 + 32 + ch32]);
        }
        // v of bg=2b+1 (cols 64..95)
        #pragma unroll
        for (int it = 0; it < 8; ++it) {
            int idx = it * 256 + t;
            int px = idx >> 5, ch32 = idx & 31;
            int sB = ch32 >> 4, ch = ch32 & 15;
            kvh[(size_t)((2 * b + 1) * HW + colrow + px) * 64 + sB * 32 + 16 + ch]
                = __float2half(smem[px * 97 + 64 + ch32]);
        }
    }
}

// ------- k2: depthwise 3x3 + LN(32) + GELU; q rows staged in LDS -------
// grid 1024 (bg*64+row), block 256: p = t&63, cq = t>>6 owns 8 channels.
// Load phase: 6 coalesced float4/thread stage rows row-1..row+1 x 32ch into LDS.
__global__ __launch_bounds__(256) void k2_off_feat(
    const float* __restrict__ wdw, const float* __restrict__ g2, const float* __restrict__ b2,
    float* __restrict__ ws)
{
    __shared__ float qtile[3][32][64];              // 24 KB
    __shared__ float rsum[4][64], rsq[4][64], smv[64], srv[64];
    const int t = threadIdx.x;
    const int bg = blockIdx.x >> 6, row = blockIdx.x & 63;
    const int p = t & 63;
    const int cq = __builtin_amdgcn_readfirstlane(t >> 6);
    const int b = bg >> 1, g = bg & 1;
    const float* qp = ws + OFF_QP;

    // stage 3 rows x 32 ch (zero-fill out-of-range rows)
    #pragma unroll
    for (int it = 0; it < 6; ++it) {
        int idx = it * 256 + t;            // 0..1535 float4 slots
        int rc = idx >> 4;                 // 0..95 (dyy*32 + ch)
        int seg = (idx & 15) << 2;
        int dyy = rc >> 5, ch = rc & 31;
        int y = row + dyy - 1;
        float4 v = make_float4(0.f, 0.f, 0.f, 0.f);
        if ((unsigned)y < 64u)
            v = *(const float4*)&qp[(size_t)(b * 64 + g * 32 + ch) * HW + y * 64 + seg];
        *(float4*)&qtile[dyy][ch][seg] = v;
    }
    __syncthreads();

    float vals[8];
    float s = 0.f, ss = 0.f;
    #pragma unroll
    for (int i = 0; i < 8; ++i) {
        int ch = cq * 8 + i;
        float a = 0.f;
        #pragma unroll
        for (int dy = 0; dy < 3; ++dy) {
            #pragma unroll
            for (int dx = 0; dx < 3; ++dx) {
                int xx = p + dx - 1;
                bool vld = (unsigned)xx < 64u;
                float q = qtile[dy][ch][vld ? xx : 0];
                a += (vld ? q : 0.f) * wdw[ch * 9 + dy * 3 + dx];
            }
        }
        vals[i] = a; s += a; ss += a * a;
    }
    rsum[cq][p] = s; rsq[cq][p] = ss;
    __syncthreads();
    if (t < 64) {
        float S = rsum[0][t] + rsum[1][t] + rsum[2][t] + rsum[3][t];
        float Q = rsq[0][t] + rsq[1][t] + rsq[2][t] + rsq[3][t];
        float m = S * (1.f / 32.f);
        float v = Q * (1.f / 32.f) - m * m;
        smv[t] = m; srv[t] = rsqrtf(v + 1e-5f);
    }
    __syncthreads();
    float m = smv[p], rv = srv[p];
    float* tb = ws + OFF_T;
    #pragma unroll
    for (int i = 0; i < 8; ++i) {
        int ch = cq * 8 + i;
        float u = (vals[i] - m) * rv * g2[ch] + b2[ch];
        float ge = 0.5f * u * (1.f + erff(u * 0.70710678118654752f));
        tb[(size_t)(bg * 32 + ch) * HW + row * 64 + p] = ge;
    }
}

// ------- k3: 3x3 conv 32->18 + tanh*5 + base offset, ic-split across waves -------
__global__ __launch_bounds__(256) void k3_pred_off(
    const float* __restrict__ boff, const float* __restrict__ off_in,
    float* __restrict__ ws)
{
    __shared__ float part[4 * 18 * 64];
    const int t = threadIdx.x;
    const int bg = blockIdx.x >> 6, row = blockIdx.x & 63;
    const int p = t & 63;
    const int icq = __builtin_amdgcn_readfirstlane(t >> 6);
    const int b = bg >> 1;
    const float* tb = ws + OFF_T;
    const float* wfT = ws + OFF_WFT;
    float acc[18];
    #pragma unroll
    for (int o = 0; o < 18; ++o) acc[o] = 0.f;
    #pragma unroll
    for (int dy = 0; dy < 3; ++dy) {
        int y = row + dy - 1;
        if ((unsigned)y >= 64u) continue;
        #pragma unroll
        for (int dx = 0; dx < 3; ++dx) {
            int xx = p + dx - 1;
            bool vld = (unsigned)xx < 64u;
            int xc = vld ? xx : 0;
            int wo = dy * 3 + dx;
            #pragma unroll
            for (int i = 0; i < 8; ++i) {
                int ic = icq * 8 + i;
                float tv = tb[(size_t)(bg * 32 + ic) * HW + y * 64 + xc];
                tv = vld ? tv : 0.f;
                const float* wrow = wfT + (wo * 32 + ic) * 18;
                #pragma unroll
                for (int o = 0; o < 18; ++o)
                    acc[o] += tv * wrow[o];
            }
        }
    }
    #pragma unroll
    for (int o = 0; o < 18; ++o) part[(icq * 18 + o) * 64 + p] = acc[o];
    __syncthreads();
    float* ob = ws + OFF_OFFB;
    #pragma unroll
    for (int r = 0; r < 5; ++r) {
        int idx = t + r * 256;
        if (idx < 1152) {
            int o = idx >> 6, p2 = idx & 63;
            float v = part[o * 64 + p2] + part[(18 + o) * 64 + p2]
                    + part[(36 + o) * 64 + p2] + part[(54 + o) * 64 + p2] + boff[o];
            v = tanhf(v) * 5.0f + off_in[(size_t)(b * 18 + o) * HW + row * 64 + p2];
            ob[(size_t)(bg * 18 + o) * HW + row * 64 + p2] = v;
        }
    }
}

// ---- k4: deformable gather + softmax attn, fp16 KV, one wave = one group ----
__global__ __launch_bounds__(256, 2) void k4_attn(
    const float* __restrict__ rpb, float* __restrict__ ws)
{
    __shared__ float rpb_l[NHD * NTAP * HC]; // 576 floats
    for (int i = threadIdx.x; i < NHD * NTAP * HC; i += 256) rpb_l[i] = rpb[i];
    __syncthreads();

    const int t = threadIdx.x;
    const int wave = __builtin_amdgcn_readfirstlane(t >> 6);
    const int g = wave & 1, pxh = wave >> 1;
    const int lane = t & 63;
    const int pxl = lane & 7;
    const int prt = lane >> 3;
    const int s    = prt >> 2;
    const int half = (prt >> 1) & 1;
    const int j    = prt & 1;
    const int b = blockIdx.x & 7;
    const int chunk = blockIdx.x >> 3;          // 0..255
    const int hw = chunk * 16 + pxh * 8 + pxl;
    const int pix = b * HW + hw;
    const int bg = b * 2 + g;
    const int head = g * 2 + s;

    const __half* qth = (const __half*)(ws + OFF_QT);
    const __half* kvh = (const __half*)(ws + OFF_KT);
    const float*  ob  = ws + OFF_OFFB;

    union F4H { float4 f; __half2 h[4]; };
    F4H qld;
    qld.f = *(const float4*)&qth[(size_t)pix * 64 + g * 32 + s * 16 + j * 8];
    const float qs = half ? 0.0f : 0.25f;
    float qv[8];
    #pragma unroll
    for (int i = 0; i < 4; ++i) {
        float2 q2 = __half22float2(qld.h[i]);
        qv[2 * i] = q2.x * qs; qv[2 * i + 1] = q2.y * qs;
    }

    const float4* rb4 = (const float4*)(rpb_l + head * (NTAP * HC) + j * 8);
    const __half* kvp = kvh + (size_t)(bg * HW) * 64 + prt * 8;

    __half2 av[NTAP][4];
    float logit[NTAP];

    #pragma unroll
    for (int n = 0; n < NTAP; ++n) {
        float r = ob[(size_t)(bg * 18 + 2 * n) * HW + hw];
        float c = ob[(size_t)(bg * 18 + 2 * n + 1) * HW + hw];
        float y0f = floorf(r), x0f = floorf(c);
        float fy = r - y0f, fx = c - x0f;
        int iy0 = (int)y0f, ix0 = (int)x0f;
        float wts[4] = { (1.f - fx) * (1.f - fy), fx * (1.f - fy),
                         (1.f - fx) * fy,         fx * fy };
        __half2 acc0 = __float2half2_rn(0.f), acc1 = acc0, acc2 = acc0, acc3 = acc0;
        #pragma unroll
        for (int corner = 0; corner < 4; ++corner) {
            int cxx = ix0 + (corner & 1);
            int cyy = iy0 + (corner >> 1);
            bool vld = ((unsigned)cxx < 64u) && ((unsigned)cyy < 64u);
            float w = vld ? wts[corner] : 0.f;
            int cxc = min(max(cxx, 0), 63);
            int cyc = min(max(cyy, 0), 63);
            F4H kv;
            kv.f = *(const float4*)&kvp[(size_t)(cyc * 64 + cxc) * 64];
            __half2 w2 = __float2half2_rn(w);
            acc0 = __hfma2(kv.h[0], w2, acc0);
            acc1 = __hfma2(kv.h[1], w2, acc1);
            acc2 = __hfma2(kv.h[2], w2, acc2);
            acc3 = __hfma2(kv.h[3], w2, acc3);
        }
        av[n][0] = acc0; av[n][1] = acc1; av[n][2] = acc2; av[n][3] = acc3;
        float4 r0 = rb4[n * 4], r1 = rb4[n * 4 + 1];
        float2 a0 = __half22float2(acc0), a1 = __half22float2(acc1);
        float2 a2 = __half22float2(acc2), a3 = __half22float2(acc3);
        float part = qv[0] * (a0.x + r0.x) + qv[1] * (a0.y + r0.y)
                   + qv[2] * (a1.x + r0.z) + qv[3] * (a1.y + r0.w)
                   + qv[4] * (a2.x + r1.x) + qv[5] * (a2.y + r1.y)
                   + qv[6] * (a3.x + r1.z) + qv[7] * (a3.y + r1.w);
        part += __shfl_xor(part, 8, 64);
        part += __shfl_xor(part, 16, 64);
        logit[n] = part;
    }

    float m = logit[0];
    #pragma unroll
    for (int n = 1; n < NTAP; ++n) m = fmaxf(m, logit[n]);
    float l = 0.f;
    #pragma unroll
    for (int n = 0; n < NTAP; ++n) { logit[n] = __expf(logit[n] - m); l += logit[n]; }
    const float inv = 1.f / l;

    __half2 o0 = __float2half2_rn(0.f), o1 = o0, o2 = o0, o3 = o0;
    #pragma unroll
    for (int n = 0; n < NTAP; ++n) {
        __half2 p2 = __float2half2_rn(logit[n]);
        o0 = __hfma2(av[n][0], p2, o0);
        o1 = __hfma2(av[n][1], p2, o1);
        o2 = __hfma2(av[n][2], p2, o2);
        o3 = __hfma2(av[n][3], p2, o3);
    }
    if (half) {   // v-lanes write
        float* ao = ws + OFF_AOT;
        const int cb = head * 16 + j * 8;
        float2 f0 = __half22float2(o0), f1 = __half22float2(o1);
        float2 f2 = __half22float2(o2), f3 = __half22float2(o3);
        ao[(size_t)(cb + 0) * BHW + pix] = f0.x * inv;
        ao[(size_t)(cb + 1) * BHW + pix] = f0.y * inv;
        ao[(size_t)(cb + 2) * BHW + pix] = f1.x * inv;
        ao[(size_t)(cb + 3) * BHW + pix] = f1.y * inv;
        ao[(size_t)(cb + 4) * BHW + pix] = f2.x * inv;
        ao[(size_t)(cb + 5) * BHW + pix] = f2.y * inv;
        ao[(size_t)(cb + 6) * BHW + pix] = f3.x * inv;
        ao[(size_t)(cb + 7) * BHW + pix] = f3.y * inv;
    }
}

// ------ k5a: proj(64->256) + bias + residual -> tmpG planar [256][B*HW] ------
__global__ __launch_bounds__(256) void k5a_proj(
    const float* __restrict__ x, const float* __restrict__ bproj,
    float* __restrict__ ws)
{
    const int t = threadIdx.x;
    const int mhalf = blockIdx.x >> 9;
    const int rb = blockIdx.x & 511;
    const int b = rb >> 6, row = rb & 63;
    const int p = t & 63;
    const int wv = __builtin_amdgcn_readfirstlane(t >> 6);
    const int cb = mhalf * 128 + wv * 32;
    const float* ao  = ws + OFF_AOT;
    const float* wpT = ws + OFF_WPT;
    float* tmpG = ws + OFF_TMPG;
    const int pixcol = row * 64 + p;
    const size_t aob = (size_t)b * HW + pixcol;

    float acc[32];
    #pragma unroll
    for (int j = 0; j < 32; ++j) acc[j] = 0.f;
    #pragma unroll 4
    for (int cr = 0; cr < 64; ++cr) {
        float av = ao[(size_t)cr * BHW + aob];
        const float* wrow = wpT + cr * 256 + cb;
        #pragma unroll
        for (int j = 0; j < 32; ++j)
            acc[j] += av * wrow[j];
    }
    #pragma unroll
    for (int j = 0; j < 32; ++j) {
        int c = cb + j;
        tmpG[(size_t)c * BHW + aob] = acc[j] + bproj[c] + x[(size_t)(b * DIM + c) * HW + pixcol];
    }
}

// ------ k5b: cls head (256->80) from tmpG ------
__global__ __launch_bounds__(256) void k5b_cls(
    const float* __restrict__ bcls, const float* __restrict__ wsr, float* __restrict__ out)
{
    const int t = threadIdx.x;
    const int ochalf = blockIdx.x >> 9;
    const int rb = blockIdx.x & 511;
    const int b = rb >> 6, row = rb & 63;
    const int p = t & 63;
    const int wv = __builtin_amdgcn_readfirstlane(t >> 6);
    const int oc0 = ochalf * 40 + wv * 10;
    const float* tmpG = wsr + OFF_TMPG;
    const float* wcT  = wsr + OFF_WCT;
    const int pixcol = row * 64 + p;
    const size_t pixb = (size_t)b * HW + pixcol;

    float acc2[10];
    #pragma unroll
    for (int j = 0; j < 10; ++j) acc2[j] = bcls[oc0 + j];
    #pragma unroll 4
    for (int c = 0; c < 256; ++c) {
        float tv = tmpG[(size_t)c * BHW + pixb];
        const float* wrow = wcT + c * 80 + oc0;
        #pragma unroll
        for (int j = 0; j < 10; ++j)
            acc2[j] += tv * wrow[j];
    }
    #pragma unroll
    for (int j = 0; j < 10; ++j)
        out[(size_t)(b * NCLS + oc0 + j) * HW + pixcol] = acc2[j];
}

extern "C" void kernel_launch(void* const* d_in, const int* in_sizes, int n_in,
                              void* d_out, int out_size, void* d_ws, size_t ws_size,
                              hipStream_t stream)
{
    const float* x     = (const float*)d_in[0];
    const float* off   = (const float*)d_in[1];
    const float* g1    = (const float*)d_in[2];
    const float* b1    = (const float*)d_in[3];
    const float* wqkv  = (const float*)d_in[4];
    const float* wdw   = (const float*)d_in[5];
    const float* g2    = (const float*)d_in[6];
    const float* b2    = (const float*)d_in[7];
    const float* woff  = (const float*)d_in[8];
    const float* boff  = (const float*)d_in[9];
    const float* rpb   = (const float*)d_in[10];
    const float* wproj = (const float*)d_in[11];
    const float* bproj = (const float*)d_in[12];
    const float* wcls  = (const float*)d_in[13];
    const float* bcls  = (const float*)d_in[14];
    float* ws  = (float*)d_ws;
    float* out = (float*)d_out;

    hipLaunchKernelGGL(k0_prep,     dim3(257),  dim3(256), 0, stream, wqkv, g1, b1, woff, wproj, wcls, ws);
    hipLaunchKernelGGL(k1_gemm,     dim3(1024), dim3(256), 0, stream, x, ws);
    hipLaunchKernelGGL(k2_off_feat, dim3(1024), dim3(256), 0, stream, wdw, g2, b2, ws);
    hipLaunchKernelGGL(k3_pred_off, dim3(1024), dim3(256), 0, stream, boff, off, ws);
    hipLaunchKernelGGL(k4_attn,     dim3(2048), dim3(256), 0, stream, rpb, ws);
    hipLaunchKernelGGL(k5a_proj,    dim3(1024), dim3(256), 0, stream, x, bproj, ws);
    hipLaunchKernelGGL(k5b_cls,     dim3(1024), dim3(256), 0, stream, bcls, ws, out);
}

// Round 11
// 251.680 us; speedup vs baseline: 1.2922x; 1.0507x over previous
//
#include <hip/hip_runtime.h>
#include <hip/hip_fp16.h>
#include <math.h>

// Problem constants
#define BB   8
#define HW   4096
#define BHW  32768
#define DIM  256
#define CR   64
#define GC   32
#define NHD  4
#define HC   16
#define NTAP 9
#define NCLS 80

// workspace layout (float offsets)
#define OFF_TMPG 0u          // k5 intermediate [256][B*HW] fp32     8,388,608
#define OFF_QP   0u          // q planar   [B][64][H][W] fp32       2,097,152
#define OFF_QT   2097152u    // q pix-major[B*HW][64] fp16          1,048,576 (floats of space)
#define OFF_KT   4194304u    // KV fp16 [BG][HW][2 sub][k16|v16]    2,097,152 (floats of space)
#define OFF_T    8388608u    // t planar   [BG][32][H][W]           2,097,152
// --- overlap region: inside OFF_T's span; k0 writes each call, k1 reads,
//     then k2 clobbers with T (k1 already done) ---
#define OFF_WBF  8388608u    // W_qkv·g1 bf16 [192][256]            24,576 float-slots (49,152 shorts)
#define OFF_AB   8437760u    // A[192], B[192]                      384
// ------------------------------------------------------------------------
#define OFF_OFFB 10485760u   // off planar [BG][18][H][W]           1,179,648
#define OFF_AOT  11665408u   // attn out   [64][B*HW] planar fp32   2,097,152
#define OFF_WPT  13762560u   // wproj^T [64][256]                   16,384
#define OFF_WCT  13778944u   // wcls^T  [256][80]                   20,480
#define OFF_WFT  13799424u   // woff^T  [9][32][18]                 5,184

typedef short bf16x8 __attribute__((ext_vector_type(8)));
typedef float f32x4  __attribute__((ext_vector_type(4)));

__device__ __forceinline__ unsigned short f2bf(float f) {
    unsigned u = __float_as_uint(f);
    unsigned r = u + 0x7FFFu + ((u >> 16) & 1u);   // round-to-nearest-even
    return (unsigned short)(r >> 16);
}

// ---------------- k0: weight prep ----------------
// blocks 0..191:  bf16 W rows  (o = blk, threads = c)
// blocks 192..447: transposes  (c = blk-192)
// block 448:       AB vectors + woff^T
__global__ __launch_bounds__(256) void k0_prep(
    const float* __restrict__ wqkv, const float* __restrict__ g1,
    const float* __restrict__ b1, const float* __restrict__ woff,
    const float* __restrict__ wproj, const float* __restrict__ wcls,
    float* __restrict__ ws)
{
    const int t = threadIdx.x;
    const int blk = blockIdx.x;
    if (blk < 192) {
        const int o = blk;
        unsigned short* wbf = (unsigned short*)(ws + OFF_WBF);
        wbf[o * 256 + t] = f2bf(wqkv[o * 256 + t] * g1[t]);
    } else if (blk < 448) {
        const int c = blk - 192;
        if (c < 64) ws[OFF_WPT + c * 256 + t] = wproj[t * 64 + c];
        if (t < 80) ws[OFF_WCT + c * 80 + t]  = wcls[t * 256 + c];
    } else {
        if (t < 192) {
            float a = 0.f, bb = 0.f;
            for (int c = 0; c < 256; ++c) {
                float w = wqkv[t * 256 + c];
                a += w * g1[c]; bb += w * b1[c];
            }
            ws[OFF_AB + t] = a;
            ws[OFF_AB + 192 + t] = bb;
            for (int pair = t; pair < 288; pair += 192) {
                int wo = pair >> 5, ic = pair & 31;
                for (int o = 0; o < 18; ++o)
                    ws[OFF_WFT + (wo * 32 + ic) * 18 + o] = woff[(o * 32 + ic) * 9 + wo];
            }
        }
    }
}

// ------ k1: QKV GEMM via bf16 MFMA, LN folded in epilogue, fp16 q/KV out ------
// grid 512 (b = blk&7 XCD-affine, row = blk>>3), block 512 = 8 waves.
// wave wv: pt = wv&3 (16-px tile), oh = wv>>2 (96-o half). 6 o-tiles x 8 k-steps.
__global__ __launch_bounds__(512) void k1_mfma(
    const float* __restrict__ x, float* __restrict__ ws)
{
    __shared__ float tile[64 * 193];   // 49.4 KB transpose tile [px][o] pad 193
    const int t = threadIdx.x;
    const int b = blockIdx.x & 7, row = blockIdx.x >> 3;
    const int wv = __builtin_amdgcn_readfirstlane(t >> 6);
    const int pt = wv & 3, oh = wv >> 2;
    const int lane = t & 63;
    const int quad = lane >> 4, pxl = lane & 15;
    const int colbase = row * 64 + pt * 16 + pxl;
    const unsigned short* wbf = (const unsigned short*)(ws + OFF_WBF);
    const float* AB = ws + OFF_AB;

    f32x4 acc[6];
    #pragma unroll
    for (int ot = 0; ot < 6; ++ot) acc[ot] = (f32x4){0.f, 0.f, 0.f, 0.f};
    float s = 0.f, ss = 0.f;
    const size_t xb0 = (size_t)b * DIM * HW + colbase;

    for (int ks = 0; ks < 8; ++ks) {
        const int cbase = ks * 32 + quad * 8;
        float xv[8];
        #pragma unroll
        for (int j = 0; j < 8; ++j) {
            xv[j] = x[xb0 + (size_t)(cbase + j) * HW];
            s += xv[j]; ss += xv[j] * xv[j];
        }
        union { bf16x8 v; unsigned short u[8]; } bfrag;
        #pragma unroll
        for (int j = 0; j < 8; ++j) bfrag.u[j] = f2bf(xv[j]);
        #pragma unroll
        for (int ot = 0; ot < 6; ++ot) {
            const int orow = (oh * 6 + ot) * 16 + pxl;
            union { float4 f; bf16x8 v; } afrag;
            afrag.f = *(const float4*)&wbf[orow * 256 + cbase];
            acc[ot] = __builtin_amdgcn_mfma_f32_16x16x32_bf16(afrag.v, bfrag.v, acc[ot], 0, 0, 0);
        }
    }

    // LN stats: reduce over quads (same px = lane&15)
    s  += __shfl_xor(s, 16, 64);  s  += __shfl_xor(s, 32, 64);
    ss += __shfl_xor(ss, 16, 64); ss += __shfl_xor(ss, 32, 64);
    const float m = s * (1.f / 256.f);
    const float rsv = rsqrtf(ss * (1.f / 256.f) - m * m + 1e-5f);

    // epilogue: LN fold, write into transpose tile. D: row=quad*4+reg, col=lane&15
    const int px = pt * 16 + pxl;
    #pragma unroll
    for (int ot = 0; ot < 6; ++ot) {
        #pragma unroll
        for (int r = 0; r < 4; ++r) {
            int o = (oh * 6 + ot) * 16 + quad * 4 + r;
            tile[px * 193 + o] = rsv * (acc[ot][r] - m * AB[o]) + AB[192 + o];
        }
    }
    __syncthreads();

    float*  qp  = ws + OFF_QP;
    __half* qth = (__half*)(ws + OFF_QT);
    __half* kvh = (__half*)(ws + OFF_KT);
    const int colrow = row * 64;
    // q planar fp32 (k2 input)
    #pragma unroll
    for (int it = 0; it < 8; ++it) {
        int idx = it * 512 + t;
        int o = idx >> 6, px2 = idx & 63;
        qp[(size_t)(b * 64 + o) * HW + colrow + px2] = tile[px2 * 193 + o];
    }
    // q pixel-major fp16 (k4 input)
    #pragma unroll
    for (int it = 0; it < 8; ++it) {
        int idx = it * 512 + t;
        int px2 = idx >> 6, o = idx & 63;
        qth[(size_t)(b * HW + colrow + px2) * 64 + o] = __float2half(tile[px2 * 193 + o]);
    }
    // k of bg=2b (o 64..95)
    #pragma unroll
    for (int it = 0; it < 4; ++it) {
        int idx = it * 512 + t;
        int px2 = idx >> 5, ch32 = idx & 31;
        int sB = ch32 >> 4, ch = ch32 & 15;
        kvh[(size_t)((2 * b) * HW + colrow + px2) * 64 + sB * 32 + ch]
            = __float2half(tile[px2 * 193 + 64 + ch32]);
    }
    // k of bg=2b+1 (o 96..127)
    #pragma unroll
    for (int it = 0; it < 4; ++it) {
        int idx = it * 512 + t;
        int px2 = idx >> 5, ch32 = idx & 31;
        int sB = ch32 >> 4, ch = ch32 & 15;
        kvh[(size_t)((2 * b + 1) * HW + colrow + px2) * 64 + sB * 32 + ch]
            = __float2half(tile[px2 * 193 + 96 + ch32]);
    }
    // v of bg=2b (o 128..159)
    #pragma unroll
    for (int it = 0; it < 4; ++it) {
        int idx = it * 512 + t;
        int px2 = idx >> 5, ch32 = idx & 31;
        int sB = ch32 >> 4, ch = ch32 & 15;
        kvh[(size_t)((2 * b) * HW + colrow + px2) * 64 + sB * 32 + 16 + ch]
            = __float2half(tile[px2 * 193 + 128 + ch32]);
    }
    // v of bg=2b+1 (o 160..191)
    #pragma unroll
    for (int it = 0; it < 4; ++it) {
        int idx = it * 512 + t;
        int px2 = idx >> 5, ch32 = idx & 31;
        int sB = ch32 >> 4, ch = ch32 & 15;
        kvh[(size_t)((2 * b + 1) * HW + colrow + px2) * 64 + sB * 32 + 16 + ch]
            = __float2half(tile[px2 * 193 + 160 + ch32]);
    }
}

// ------- k2: depthwise 3x3 + LN(32) + GELU; q rows staged in LDS -------
__global__ __launch_bounds__(256) void k2_off_feat(
    const float* __restrict__ wdw, const float* __restrict__ g2, const float* __restrict__ b2,
    float* __restrict__ ws)
{
    __shared__ float qtile[3][32][64];              // 24 KB
    __shared__ float rsum[4][64], rsq[4][64], smv[64], srv[64];
    const int t = threadIdx.x;
    const int bg = blockIdx.x >> 6, row = blockIdx.x & 63;
    const int p = t & 63;
    const int cq = __builtin_amdgcn_readfirstlane(t >> 6);
    const int b = bg >> 1, g = bg & 1;
    const float* qp = ws + OFF_QP;

    #pragma unroll
    for (int it = 0; it < 6; ++it) {
        int idx = it * 256 + t;
        int rc = idx >> 4;
        int seg = (idx & 15) << 2;
        int dyy = rc >> 5, ch = rc & 31;
        int y = row + dyy - 1;
        float4 v = make_float4(0.f, 0.f, 0.f, 0.f);
        if ((unsigned)y < 64u)
            v = *(const float4*)&qp[(size_t)(b * 64 + g * 32 + ch) * HW + y * 64 + seg];
        *(float4*)&qtile[dyy][ch][seg] = v;
    }
    __syncthreads();

    float vals[8];
    float s = 0.f, ss = 0.f;
    #pragma unroll
    for (int i = 0; i < 8; ++i) {
        int ch = cq * 8 + i;
        float a = 0.f;
        #pragma unroll
        for (int dy = 0; dy < 3; ++dy) {
            #pragma unroll
            for (int dx = 0; dx < 3; ++dx) {
                int xx = p + dx - 1;
                bool vld = (unsigned)xx < 64u;
                float q = qtile[dy][ch][vld ? xx : 0];
                a += (vld ? q : 0.f) * wdw[ch * 9 + dy * 3 + dx];
            }
        }
        vals[i] = a; s += a; ss += a * a;
    }
    rsum[cq][p] = s; rsq[cq][p] = ss;
    __syncthreads();
    if (t < 64) {
        float S = rsum[0][t] + rsum[1][t] + rsum[2][t] + rsum[3][t];
        float Q = rsq[0][t] + rsq[1][t] + rsq[2][t] + rsq[3][t];
        float m = S * (1.f / 32.f);
        float v = Q * (1.f / 32.f) - m * m;
        smv[t] = m; srv[t] = rsqrtf(v + 1e-5f);
    }
    __syncthreads();
    float m = smv[p], rv = srv[p];
    float* tb = ws + OFF_T;
    #pragma unroll
    for (int i = 0; i < 8; ++i) {
        int ch = cq * 8 + i;
        float u = (vals[i] - m) * rv * g2[ch] + b2[ch];
        float ge = 0.5f * u * (1.f + erff(u * 0.70710678118654752f));
        tb[(size_t)(bg * 32 + ch) * HW + row * 64 + p] = ge;
    }
}

// ------- k3: 3x3 conv 32->18 + tanh*5 + base offset, ic-split across waves -------
__global__ __launch_bounds__(256) void k3_pred_off(
    const float* __restrict__ boff, const float* __restrict__ off_in,
    float* __restrict__ ws)
{
    __shared__ float part[4 * 18 * 64];
    const int t = threadIdx.x;
    const int bg = blockIdx.x >> 6, row = blockIdx.x & 63;
    const int p = t & 63;
    const int icq = __builtin_amdgcn_readfirstlane(t >> 6);
    const int b = bg >> 1;
    const float* tb = ws + OFF_T;
    const float* wfT = ws + OFF_WFT;
    float acc[18];
    #pragma unroll
    for (int o = 0; o < 18; ++o) acc[o] = 0.f;
    #pragma unroll
    for (int dy = 0; dy < 3; ++dy) {
        int y = row + dy - 1;
        if ((unsigned)y >= 64u) continue;
        #pragma unroll
        for (int dx = 0; dx < 3; ++dx) {
            int xx = p + dx - 1;
            bool vld = (unsigned)xx < 64u;
            int xc = vld ? xx : 0;
            int wo = dy * 3 + dx;
            #pragma unroll
            for (int i = 0; i < 8; ++i) {
                int ic = icq * 8 + i;
                float tv = tb[(size_t)(bg * 32 + ic) * HW + y * 64 + xc];
                tv = vld ? tv : 0.f;
                const float* wrow = wfT + (wo * 32 + ic) * 18;
                #pragma unroll
                for (int o = 0; o < 18; ++o)
                    acc[o] += tv * wrow[o];
            }
        }
    }
    #pragma unroll
    for (int o = 0; o < 18; ++o) part[(icq * 18 + o) * 64 + p] = acc[o];
    __syncthreads();
    float* ob = ws + OFF_OFFB;
    #pragma unroll
    for (int r = 0; r < 5; ++r) {
        int idx = t + r * 256;
        if (idx < 1152) {
            int o = idx >> 6, p2 = idx & 63;
            float v = part[o * 64 + p2] + part[(18 + o) * 64 + p2]
                    + part[(36 + o) * 64 + p2] + part[(54 + o) * 64 + p2] + boff[o];
            v = tanhf(v) * 5.0f + off_in[(size_t)(b * 18 + o) * HW + row * 64 + p2];
            ob[(size_t)(bg * 18 + o) * HW + row * 64 + p2] = v;
        }
    }
}

// ---- k4: deformable gather + softmax attn, fp16 KV, one wave = one group ----
__global__ __launch_bounds__(256, 2) void k4_attn(
    const float* __restrict__ rpb, float* __restrict__ ws)
{
    __shared__ float rpb_l[NHD * NTAP * HC]; // 576 floats
    for (int i = threadIdx.x; i < NHD * NTAP * HC; i += 256) rpb_l[i] = rpb[i];
    __syncthreads();

    const int t = threadIdx.x;
    const int wave = __builtin_amdgcn_readfirstlane(t >> 6);
    const int g = wave & 1, pxh = wave >> 1;
    const int lane = t & 63;
    const int pxl = lane & 7;
    const int prt = lane >> 3;
    const int s    = prt >> 2;
    const int half = (prt >> 1) & 1;
    const int j    = prt & 1;
    const int b = blockIdx.x & 7;
    const int chunk = blockIdx.x >> 3;          // 0..255
    const int hw = chunk * 16 + pxh * 8 + pxl;
    const int pix = b * HW + hw;
    const int bg = b * 2 + g;
    const int head = g * 2 + s;

    const __half* qth = (const __half*)(ws + OFF_QT);
    const __half* kvh = (const __half*)(ws + OFF_KT);
    const float*  ob  = ws + OFF_OFFB;

    union F4H { float4 f; __half2 h[4]; };
    F4H qld;
    qld.f = *(const float4*)&qth[(size_t)pix * 64 + g * 32 + s * 16 + j * 8];
    const float qs = half ? 0.0f : 0.25f;
    float qv[8];
    #pragma unroll
    for (int i = 0; i < 4; ++i) {
        float2 q2 = __half22float2(qld.h[i]);
        qv[2 * i] = q2.x * qs; qv[2 * i + 1] = q2.y * qs;
    }

    const float4* rb4 = (const float4*)(rpb_l + head * (NTAP * HC) + j * 8);
    const __half* kvp = kvh + (size_t)(bg * HW) * 64 + prt * 8;

    __half2 av[NTAP][4];
    float logit[NTAP];

    #pragma unroll
    for (int n = 0; n < NTAP; ++n) {
        float r = ob[(size_t)(bg * 18 + 2 * n) * HW + hw];
        float c = ob[(size_t)(bg * 18 + 2 * n + 1) * HW + hw];
        float y0f = floorf(r), x0f = floorf(c);
        float fy = r - y0f, fx = c - x0f;
        int iy0 = (int)y0f, ix0 = (int)x0f;
        float wts[4] = { (1.f - fx) * (1.f - fy), fx * (1.f - fy),
                         (1.f - fx) * fy,         fx * fy };
        __half2 acc0 = __float2half2_rn(0.f), acc1 = acc0, acc2 = acc0, acc3 = acc0;
        #pragma unroll
        for (int corner = 0; corner < 4; ++corner) {
            int cxx = ix0 + (corner & 1);
            int cyy = iy0 + (corner >> 1);
            bool vld = ((unsigned)cxx < 64u) && ((unsigned)cyy < 64u);
            float w = vld ? wts[corner] : 0.f;
            int cxc = min(max(cxx, 0), 63);
            int cyc = min(max(cyy, 0), 63);
            F4H kv;
            kv.f = *(const float4*)&kvp[(size_t)(cyc * 64 + cxc) * 64];
            __half2 w2 = __float2half2_rn(w);
            acc0 = __hfma2(kv.h[0], w2, acc0);
            acc1 = __hfma2(kv.h[1], w2, acc1);
            acc2 = __hfma2(kv.h[2], w2, acc2);
            acc3 = __hfma2(kv.h[3], w2, acc3);
        }
        av[n][0] = acc0; av[n][1] = acc1; av[n][2] = acc2; av[n][3] = acc3;
        float4 r0 = rb4[n * 4], r1 = rb4[n * 4 + 1];
        float2 a0 = __half22float2(acc0), a1 = __half22float2(acc1);
        float2 a2 = __half22float2(acc2), a3 = __half22float2(acc3);
        float part = qv[0] * (a0.x + r0.x) + qv[1] * (a0.y + r0.y)
                   + qv[2] * (a1.x + r0.z) + qv[3] * (a1.y + r0.w)
                   + qv[4] * (a2.x + r1.x) + qv[5] * (a2.y + r1.y)
                   + qv[6] * (a3.x + r1.z) + qv[7] * (a3.y + r1.w);
        part += __shfl_xor(part, 8, 64);
        part += __shfl_xor(part, 16, 64);
        logit[n] = part;
    }

    float m = logit[0];
    #pragma unroll
    for (int n = 1; n < NTAP; ++n) m = fmaxf(m, logit[n]);
    float l = 0.f;
    #pragma unroll
    for (int n = 0; n < NTAP; ++n) { logit[n] = __expf(logit[n] - m); l += logit[n]; }
    const float inv = 1.f / l;

    __half2 o0 = __float2half2_rn(0.f), o1 = o0, o2 = o0, o3 = o0;
    #pragma unroll
    for (int n = 0; n < NTAP; ++n) {
        __half2 p2 = __float2half2_rn(logit[n]);
        o0 = __hfma2(av[n][0], p2, o0);
        o1 = __hfma2(av[n][1], p2, o1);
        o2 = __hfma2(av[n][2], p2, o2);
        o3 = __hfma2(av[n][3], p2, o3);
    }
    if (half) {   // v-lanes write
        float* ao = ws + OFF_AOT;
        const int cb = head * 16 + j * 8;
        float2 f0 = __half22float2(o0), f1 = __half22float2(o1);
        float2 f2 = __half22float2(o2), f3 = __half22float2(o3);
        ao[(size_t)(cb + 0) * BHW + pix] = f0.x * inv;
        ao[(size_t)(cb + 1) * BHW + pix] = f0.y * inv;
        ao[(size_t)(cb + 2) * BHW + pix] = f1.x * inv;
        ao[(size_t)(cb + 3) * BHW + pix] = f1.y * inv;
        ao[(size_t)(cb + 4) * BHW + pix] = f2.x * inv;
        ao[(size_t)(cb + 5) * BHW + pix] = f2.y * inv;
        ao[(size_t)(cb + 6) * BHW + pix] = f3.x * inv;
        ao[(size_t)(cb + 7) * BHW + pix] = f3.y * inv;
    }
}

// ------ k5a: proj(64->256) + bias + residual -> tmpG planar [256][B*HW] ------
__global__ __launch_bounds__(256) void k5a_proj(
    const float* __restrict__ x, const float* __restrict__ bproj,
    float* __restrict__ ws)
{
    const int t = threadIdx.x;
    const int mhalf = blockIdx.x >> 9;
    const int rb = blockIdx.x & 511;
    const int b = rb >> 6, row = rb & 63;
    const int p = t & 63;
    const int wv = __builtin_amdgcn_readfirstlane(t >> 6);
    const int cb = mhalf * 128 + wv * 32;
    const float* ao  = ws + OFF_AOT;
    const float* wpT = ws + OFF_WPT;
    float* tmpG = ws + OFF_TMPG;
    const int pixcol = row * 64 + p;
    const size_t aob = (size_t)b * HW + pixcol;

    float acc[32];
    #pragma unroll
    for (int j = 0; j < 32; ++j) acc[j] = 0.f;
    #pragma unroll 4
    for (int cr = 0; cr < 64; ++cr) {
        float av = ao[(size_t)cr * BHW + aob];
        const float* wrow = wpT + cr * 256 + cb;
        #pragma unroll
        for (int j = 0; j < 32; ++j)
            acc[j] += av * wrow[j];
    }
    #pragma unroll
    for (int j = 0; j < 32; ++j) {
        int c = cb + j;
        tmpG[(size_t)c * BHW + aob] = acc[j] + bproj[c] + x[(size_t)(b * DIM + c) * HW + pixcol];
    }
}

// ------ k5b: cls head (256->80) from tmpG ------
__global__ __launch_bounds__(256) void k5b_cls(
    const float* __restrict__ bcls, const float* __restrict__ wsr, float* __restrict__ out)
{
    const int t = threadIdx.x;
    const int ochalf = blockIdx.x >> 9;
    const int rb = blockIdx.x & 511;
    const int b = rb >> 6, row = rb & 63;
    const int p = t & 63;
    const int wv = __builtin_amdgcn_readfirstlane(t >> 6);
    const int oc0 = ochalf * 40 + wv * 10;
    const float* tmpG = wsr + OFF_TMPG;
    const float* wcT  = wsr + OFF_WCT;
    const int pixcol = row * 64 + p;
    const size_t pixb = (size_t)b * HW + pixcol;

    float acc2[10];
    #pragma unroll
    for (int j = 0; j < 10; ++j) acc2[j] = bcls[oc0 + j];
    #pragma unroll 4
    for (int c = 0; c < 256; ++c) {
        float tv = tmpG[(size_t)c * BHW + pixb];
        const float* wrow = wcT + c * 80 + oc0;
        #pragma unroll
        for (int j = 0; j < 10; ++j)
            acc2[j] += tv * wrow[j];
    }
    #pragma unroll
    for (int j = 0; j < 10; ++j)
        out[(size_t)(b * NCLS + oc0 + j) * HW + pixcol] = acc2[j];
}

extern "C" void kernel_launch(void* const* d_in, const int* in_sizes, int n_in,
                              void* d_out, int out_size, void* d_ws, size_t ws_size,
                              hipStream_t stream)
{
    const float* x     = (const float*)d_in[0];
    const float* off   = (const float*)d_in[1];
    const float* g1    = (const float*)d_in[2];
    const float* b1    = (const float*)d_in[3];
    const float* wqkv  = (const float*)d_in[4];
    const float* wdw   = (const float*)d_in[5];
    const float* g2    = (const float*)d_in[6];
    const float* b2    = (const float*)d_in[7];
    const float* woff  = (const float*)d_in[8];
    const float* boff  = (const float*)d_in[9];
    const float* rpb   = (const float*)d_in[10];
    const float* wproj = (const float*)d_in[11];
    const float* bproj = (const float*)d_in[12];
    const float* wcls  = (const float*)d_in[13];
    const float* bcls  = (const float*)d_in[14];
    float* ws  = (float*)d_ws;
    float* out = (float*)d_out;

    hipLaunchKernelGGL(k0_prep,     dim3(449),  dim3(256), 0, stream, wqkv, g1, b1, woff, wproj, wcls, ws);
    hipLaunchKernelGGL(k1_mfma,     dim3(512),  dim3(512), 0, stream, x, ws);
    hipLaunchKernelGGL(k2_off_feat, dim3(1024), dim3(256), 0, stream, wdw, g2, b2, ws);
    hipLaunchKernelGGL(k3_pred_off, dim3(1024), dim3(256), 0, stream, boff, off, ws);
    hipLaunchKernelGGL(k4_attn,     dim3(2048), dim3(256), 0, stream, rpb, ws);
    hipLaunchKernelGGL(k5a_proj,    dim3(1024), dim3(256), 0, stream, x, bproj, ws);
    hipLaunchKernelGGL(k5b_cls,     dim3(1024), dim3(256), 0, stream, bcls, ws, out);
}

// Round 12
// 238.721 us; speedup vs baseline: 1.3624x; 1.0543x over previous
//
#include <hip/hip_runtime.h>
#include <hip/hip_fp16.h>
#include <math.h>

// Problem constants
#define BB   8
#define HW   4096
#define BHW  32768
#define DIM  256
#define CR   64
#define GC   32
#define NHD  4
#define HC   16
#define NTAP 9
#define NCLS 80

// workspace layout (float offsets)
#define OFF_QP   0u          // q planar   [B][64][H][W] fp32       2,097,152
#define OFF_QT   2097152u    // q pix-major[B*HW][64] fp16          1,048,576 (floats of space)
#define OFF_KT   4194304u    // KV fp16 [BG][HW][2 sub][k16|v16]    2,097,152 (floats of space)
#define OFF_T    8388608u    // t planar   [BG][32][H][W]           2,097,152
// --- overlap region: inside OFF_T's span; k0 writes each call, k1 reads,
//     then k2 clobbers with T (k1 already done) ---
#define OFF_WBF  8388608u    // W_qkv·g1 bf16 [192][256]            24,576 float-slots
#define OFF_AB   8437760u    // A[192], B[192]                      384
// ------------------------------------------------------------------------
#define OFF_OFFB 10485760u   // off planar [BG][18][H][W]           1,179,648
#define OFF_AOT  11665408u   // attn out bf16 [B*HW][64] pix-major  1,048,576 float-slots used
#define OFF_WPT  13762560u   // wproj bf16 [256][64]                8,192 float-slots used
#define OFF_WCT  13778944u   // wcls  bf16 [80][256]                10,240 float-slots used
#define OFF_WFT  13799424u   // woff^T  [9][32][18]                 5,184

typedef short bf16x8 __attribute__((ext_vector_type(8)));
typedef float f32x4  __attribute__((ext_vector_type(4)));

__device__ __forceinline__ unsigned short f2bf(float f) {
    unsigned u = __float_as_uint(f);
    unsigned r = u + 0x7FFFu + ((u >> 16) & 1u);   // round-to-nearest-even
    return (unsigned short)(r >> 16);
}

// ---------------- k0: weight prep ----------------
// blocks 0..191:  bf16 Wqkv·g1 rows (o = blk, threads = c)
// blocks 192..447: bf16 wproj/wcls rows (r = blk-192)
// block 448:       AB vectors + woff^T
__global__ __launch_bounds__(256) void k0_prep(
    const float* __restrict__ wqkv, const float* __restrict__ g1,
    const float* __restrict__ b1, const float* __restrict__ woff,
    const float* __restrict__ wproj, const float* __restrict__ wcls,
    float* __restrict__ ws)
{
    const int t = threadIdx.x;
    const int blk = blockIdx.x;
    if (blk < 192) {
        const int o = blk;
        unsigned short* wbf = (unsigned short*)(ws + OFF_WBF);
        wbf[o * 256 + t] = f2bf(wqkv[o * 256 + t] * g1[t]);
    } else if (blk < 448) {
        const int r = blk - 192;   // 0..255
        unsigned short* wpb = (unsigned short*)(ws + OFF_WPT);
        unsigned short* wcb = (unsigned short*)(ws + OFF_WCT);
        if (t < 64) wpb[r * 64 + t] = f2bf(wproj[r * 64 + t]);
        if (r < 80) wcb[r * 256 + t] = f2bf(wcls[r * 256 + t]);
    } else {
        if (t < 192) {
            float a = 0.f, bb = 0.f;
            for (int c = 0; c < 256; ++c) {
                float w = wqkv[t * 256 + c];
                a += w * g1[c]; bb += w * b1[c];
            }
            ws[OFF_AB + t] = a;
            ws[OFF_AB + 192 + t] = bb;
            for (int pair = t; pair < 288; pair += 192) {
                int wo = pair >> 5, ic = pair & 31;
                for (int o = 0; o < 18; ++o)
                    ws[OFF_WFT + (wo * 32 + ic) * 18 + o] = woff[(o * 32 + ic) * 9 + wo];
            }
        }
    }
}

// ------ k1: QKV GEMM via bf16 MFMA, LN folded in epilogue, fp16 q/KV out ------
// grid 512 (b = blk&7 XCD-affine, row = blk>>3), block 512 = 8 waves.
__global__ __launch_bounds__(512) void k1_mfma(
    const float* __restrict__ x, float* __restrict__ ws)
{
    __shared__ float tile[64 * 193];   // 49.4 KB transpose tile [px][o] pad 193
    const int t = threadIdx.x;
    const int b = blockIdx.x & 7, row = blockIdx.x >> 3;
    const int wv = __builtin_amdgcn_readfirstlane(t >> 6);
    const int pt = wv & 3, oh = wv >> 2;
    const int lane = t & 63;
    const int quad = lane >> 4, pxl = lane & 15;
    const int colbase = row * 64 + pt * 16 + pxl;
    const unsigned short* wbf = (const unsigned short*)(ws + OFF_WBF);
    const float* AB = ws + OFF_AB;

    f32x4 acc[6];
    #pragma unroll
    for (int ot = 0; ot < 6; ++ot) acc[ot] = (f32x4){0.f, 0.f, 0.f, 0.f};
    float s = 0.f, ss = 0.f;
    const size_t xb0 = (size_t)b * DIM * HW + colbase;

    for (int ks = 0; ks < 8; ++ks) {
        const int cbase = ks * 32 + quad * 8;
        float xv[8];
        #pragma unroll
        for (int j = 0; j < 8; ++j) {
            xv[j] = x[xb0 + (size_t)(cbase + j) * HW];
            s += xv[j]; ss += xv[j] * xv[j];
        }
        union { bf16x8 v; unsigned short u[8]; } bfrag;
        #pragma unroll
        for (int j = 0; j < 8; ++j) bfrag.u[j] = f2bf(xv[j]);
        #pragma unroll
        for (int ot = 0; ot < 6; ++ot) {
            const int orow = (oh * 6 + ot) * 16 + pxl;
            union { float4 f; bf16x8 v; } afrag;
            afrag.f = *(const float4*)&wbf[orow * 256 + cbase];
            acc[ot] = __builtin_amdgcn_mfma_f32_16x16x32_bf16(afrag.v, bfrag.v, acc[ot], 0, 0, 0);
        }
    }

    s  += __shfl_xor(s, 16, 64);  s  += __shfl_xor(s, 32, 64);
    ss += __shfl_xor(ss, 16, 64); ss += __shfl_xor(ss, 32, 64);
    const float m = s * (1.f / 256.f);
    const float rsv = rsqrtf(ss * (1.f / 256.f) - m * m + 1e-5f);

    const int px = pt * 16 + pxl;
    #pragma unroll
    for (int ot = 0; ot < 6; ++ot) {
        #pragma unroll
        for (int r = 0; r < 4; ++r) {
            int o = (oh * 6 + ot) * 16 + quad * 4 + r;
            tile[px * 193 + o] = rsv * (acc[ot][r] - m * AB[o]) + AB[192 + o];
        }
    }
    __syncthreads();

    float*  qp  = ws + OFF_QP;
    __half* qth = (__half*)(ws + OFF_QT);
    __half* kvh = (__half*)(ws + OFF_KT);
    const int colrow = row * 64;
    #pragma unroll
    for (int it = 0; it < 8; ++it) {
        int idx = it * 512 + t;
        int o = idx >> 6, px2 = idx & 63;
        qp[(size_t)(b * 64 + o) * HW + colrow + px2] = tile[px2 * 193 + o];
    }
    #pragma unroll
    for (int it = 0; it < 8; ++it) {
        int idx = it * 512 + t;
        int px2 = idx >> 6, o = idx & 63;
        qth[(size_t)(b * HW + colrow + px2) * 64 + o] = __float2half(tile[px2 * 193 + o]);
    }
    #pragma unroll
    for (int it = 0; it < 4; ++it) {
        int idx = it * 512 + t;
        int px2 = idx >> 5, ch32 = idx & 31;
        int sB = ch32 >> 4, ch = ch32 & 15;
        kvh[(size_t)((2 * b) * HW + colrow + px2) * 64 + sB * 32 + ch]
            = __float2half(tile[px2 * 193 + 64 + ch32]);
    }
    #pragma unroll
    for (int it = 0; it < 4; ++it) {
        int idx = it * 512 + t;
        int px2 = idx >> 5, ch32 = idx & 31;
        int sB = ch32 >> 4, ch = ch32 & 15;
        kvh[(size_t)((2 * b + 1) * HW + colrow + px2) * 64 + sB * 32 + ch]
            = __float2half(tile[px2 * 193 + 96 + ch32]);
    }
    #pragma unroll
    for (int it = 0; it < 4; ++it) {
        int idx = it * 512 + t;
        int px2 = idx >> 5, ch32 = idx & 31;
        int sB = ch32 >> 4, ch = ch32 & 15;
        kvh[(size_t)((2 * b) * HW + colrow + px2) * 64 + sB * 32 + 16 + ch]
            = __float2half(tile[px2 * 193 + 128 + ch32]);
    }
    #pragma unroll
    for (int it = 0; it < 4; ++it) {
        int idx = it * 512 + t;
        int px2 = idx >> 5, ch32 = idx & 31;
        int sB = ch32 >> 4, ch = ch32 & 15;
        kvh[(size_t)((2 * b + 1) * HW + colrow + px2) * 64 + sB * 32 + 16 + ch]
            = __float2half(tile[px2 * 193 + 160 + ch32]);
    }
}

// ------- k2: depthwise 3x3 + LN(32) + GELU; q rows staged in LDS -------
__global__ __launch_bounds__(256) void k2_off_feat(
    const float* __restrict__ wdw, const float* __restrict__ g2, const float* __restrict__ b2,
    float* __restrict__ ws)
{
    __shared__ float qtile[3][32][64];              // 24 KB
    __shared__ float rsum[4][64], rsq[4][64], smv[64], srv[64];
    const int t = threadIdx.x;
    const int bg = blockIdx.x >> 6, row = blockIdx.x & 63;
    const int p = t & 63;
    const int cq = __builtin_amdgcn_readfirstlane(t >> 6);
    const int b = bg >> 1, g = bg & 1;
    const float* qp = ws + OFF_QP;

    #pragma unroll
    for (int it = 0; it < 6; ++it) {
        int idx = it * 256 + t;
        int rc = idx >> 4;
        int seg = (idx & 15) << 2;
        int dyy = rc >> 5, ch = rc & 31;
        int y = row + dyy - 1;
        float4 v = make_float4(0.f, 0.f, 0.f, 0.f);
        if ((unsigned)y < 64u)
            v = *(const float4*)&qp[(size_t)(b * 64 + g * 32 + ch) * HW + y * 64 + seg];
        *(float4*)&qtile[dyy][ch][seg] = v;
    }
    __syncthreads();

    float vals[8];
    float s = 0.f, ss = 0.f;
    #pragma unroll
    for (int i = 0; i < 8; ++i) {
        int ch = cq * 8 + i;
        float a = 0.f;
        #pragma unroll
        for (int dy = 0; dy < 3; ++dy) {
            #pragma unroll
            for (int dx = 0; dx < 3; ++dx) {
                int xx = p + dx - 1;
                bool vld = (unsigned)xx < 64u;
                float q = qtile[dy][ch][vld ? xx : 0];
                a += (vld ? q : 0.f) * wdw[ch * 9 + dy * 3 + dx];
            }
        }
        vals[i] = a; s += a; ss += a * a;
    }
    rsum[cq][p] = s; rsq[cq][p] = ss;
    __syncthreads();
    if (t < 64) {
        float S = rsum[0][t] + rsum[1][t] + rsum[2][t] + rsum[3][t];
        float Q = rsq[0][t] + rsq[1][t] + rsq[2][t] + rsq[3][t];
        float m = S * (1.f / 32.f);
        float v = Q * (1.f / 32.f) - m * m;
        smv[t] = m; srv[t] = rsqrtf(v + 1e-5f);
    }
    __syncthreads();
    float m = smv[p], rv = srv[p];
    float* tb = ws + OFF_T;
    #pragma unroll
    for (int i = 0; i < 8; ++i) {
        int ch = cq * 8 + i;
        float u = (vals[i] - m) * rv * g2[ch] + b2[ch];
        float ge = 0.5f * u * (1.f + erff(u * 0.70710678118654752f));
        tb[(size_t)(bg * 32 + ch) * HW + row * 64 + p] = ge;
    }
}

// ------- k3: 3x3 conv 32->18 + tanh*5 + base offset, ic-split across waves -------
__global__ __launch_bounds__(256) void k3_pred_off(
    const float* __restrict__ boff, const float* __restrict__ off_in,
    float* __restrict__ ws)
{
    __shared__ float part[4 * 18 * 64];
    const int t = threadIdx.x;
    const int bg = blockIdx.x >> 6, row = blockIdx.x & 63;
    const int p = t & 63;
    const int icq = __builtin_amdgcn_readfirstlane(t >> 6);
    const int b = bg >> 1;
    const float* tb = ws + OFF_T;
    const float* wfT = ws + OFF_WFT;
    float acc[18];
    #pragma unroll
    for (int o = 0; o < 18; ++o) acc[o] = 0.f;
    #pragma unroll
    for (int dy = 0; dy < 3; ++dy) {
        int y = row + dy - 1;
        if ((unsigned)y >= 64u) continue;
        #pragma unroll
        for (int dx = 0; dx < 3; ++dx) {
            int xx = p + dx - 1;
            bool vld = (unsigned)xx < 64u;
            int xc = vld ? xx : 0;
            int wo = dy * 3 + dx;
            #pragma unroll
            for (int i = 0; i < 8; ++i) {
                int ic = icq * 8 + i;
                float tv = tb[(size_t)(bg * 32 + ic) * HW + y * 64 + xc];
                tv = vld ? tv : 0.f;
                const float* wrow = wfT + (wo * 32 + ic) * 18;
                #pragma unroll
                for (int o = 0; o < 18; ++o)
                    acc[o] += tv * wrow[o];
            }
        }
    }
    #pragma unroll
    for (int o = 0; o < 18; ++o) part[(icq * 18 + o) * 64 + p] = acc[o];
    __syncthreads();
    float* ob = ws + OFF_OFFB;
    #pragma unroll
    for (int r = 0; r < 5; ++r) {
        int idx = t + r * 256;
        if (idx < 1152) {
            int o = idx >> 6, p2 = idx & 63;
            float v = part[o * 64 + p2] + part[(18 + o) * 64 + p2]
                    + part[(36 + o) * 64 + p2] + part[(54 + o) * 64 + p2] + boff[o];
            v = tanhf(v) * 5.0f + off_in[(size_t)(b * 18 + o) * HW + row * 64 + p2];
            ob[(size_t)(bg * 18 + o) * HW + row * 64 + p2] = v;
        }
    }
}

// ---- k4: deformable gather + softmax attn, fp16 KV; ao out = bf16 pix-major ----
__global__ __launch_bounds__(256, 2) void k4_attn(
    const float* __restrict__ rpb, float* __restrict__ ws)
{
    __shared__ float rpb_l[NHD * NTAP * HC]; // 576 floats
    for (int i = threadIdx.x; i < NHD * NTAP * HC; i += 256) rpb_l[i] = rpb[i];
    __syncthreads();

    const int t = threadIdx.x;
    const int wave = __builtin_amdgcn_readfirstlane(t >> 6);
    const int g = wave & 1, pxh = wave >> 1;
    const int lane = t & 63;
    const int pxl = lane & 7;
    const int prt = lane >> 3;
    const int s    = prt >> 2;
    const int half = (prt >> 1) & 1;
    const int j    = prt & 1;
    const int b = blockIdx.x & 7;
    const int chunk = blockIdx.x >> 3;          // 0..255
    const int hw = chunk * 16 + pxh * 8 + pxl;
    const int pix = b * HW + hw;
    const int bg = b * 2 + g;
    const int head = g * 2 + s;

    const __half* qth = (const __half*)(ws + OFF_QT);
    const __half* kvh = (const __half*)(ws + OFF_KT);
    const float*  ob  = ws + OFF_OFFB;

    union F4H { float4 f; __half2 h[4]; };
    F4H qld;
    qld.f = *(const float4*)&qth[(size_t)pix * 64 + g * 32 + s * 16 + j * 8];
    const float qs = half ? 0.0f : 0.25f;
    float qv[8];
    #pragma unroll
    for (int i = 0; i < 4; ++i) {
        float2 q2 = __half22float2(qld.h[i]);
        qv[2 * i] = q2.x * qs; qv[2 * i + 1] = q2.y * qs;
    }

    const float4* rb4 = (const float4*)(rpb_l + head * (NTAP * HC) + j * 8);
    const __half* kvp = kvh + (size_t)(bg * HW) * 64 + prt * 8;

    __half2 av[NTAP][4];
    float logit[NTAP];

    #pragma unroll
    for (int n = 0; n < NTAP; ++n) {
        float r = ob[(size_t)(bg * 18 + 2 * n) * HW + hw];
        float c = ob[(size_t)(bg * 18 + 2 * n + 1) * HW + hw];
        float y0f = floorf(r), x0f = floorf(c);
        float fy = r - y0f, fx = c - x0f;
        int iy0 = (int)y0f, ix0 = (int)x0f;
        float wts[4] = { (1.f - fx) * (1.f - fy), fx * (1.f - fy),
                         (1.f - fx) * fy,         fx * fy };
        __half2 acc0 = __float2half2_rn(0.f), acc1 = acc0, acc2 = acc0, acc3 = acc0;
        #pragma unroll
        for (int corner = 0; corner < 4; ++corner) {
            int cxx = ix0 + (corner & 1);
            int cyy = iy0 + (corner >> 1);
            bool vld = ((unsigned)cxx < 64u) && ((unsigned)cyy < 64u);
            float w = vld ? wts[corner] : 0.f;
            int cxc = min(max(cxx, 0), 63);
            int cyc = min(max(cyy, 0), 63);
            F4H kv;
            kv.f = *(const float4*)&kvp[(size_t)(cyc * 64 + cxc) * 64];
            __half2 w2 = __float2half2_rn(w);
            acc0 = __hfma2(kv.h[0], w2, acc0);
            acc1 = __hfma2(kv.h[1], w2, acc1);
            acc2 = __hfma2(kv.h[2], w2, acc2);
            acc3 = __hfma2(kv.h[3], w2, acc3);
        }
        av[n][0] = acc0; av[n][1] = acc1; av[n][2] = acc2; av[n][3] = acc3;
        float4 r0 = rb4[n * 4], r1 = rb4[n * 4 + 1];
        float2 a0 = __half22float2(acc0), a1 = __half22float2(acc1);
        float2 a2 = __half22float2(acc2), a3 = __half22float2(acc3);
        float part = qv[0] * (a0.x + r0.x) + qv[1] * (a0.y + r0.y)
                   + qv[2] * (a1.x + r0.z) + qv[3] * (a1.y + r0.w)
                   + qv[4] * (a2.x + r1.x) + qv[5] * (a2.y + r1.y)
                   + qv[6] * (a3.x + r1.z) + qv[7] * (a3.y + r1.w);
        part += __shfl_xor(part, 8, 64);
        part += __shfl_xor(part, 16, 64);
        logit[n] = part;
    }

    float m = logit[0];
    #pragma unroll
    for (int n = 1; n < NTAP; ++n) m = fmaxf(m, logit[n]);
    float l = 0.f;
    #pragma unroll
    for (int n = 0; n < NTAP; ++n) { logit[n] = __expf(logit[n] - m); l += logit[n]; }
    const float inv = 1.f / l;

    __half2 o0 = __float2half2_rn(0.f), o1 = o0, o2 = o0, o3 = o0;
    #pragma unroll
    for (int n = 0; n < NTAP; ++n) {
        __half2 p2 = __float2half2_rn(logit[n]);
        o0 = __hfma2(av[n][0], p2, o0);
        o1 = __hfma2(av[n][1], p2, o1);
        o2 = __hfma2(av[n][2], p2, o2);
        o3 = __hfma2(av[n][3], p2, o3);
    }
    if (half) {   // v-lanes write ao bf16 pixel-major [pix][64]
        unsigned short* aob = (unsigned short*)(ws + OFF_AOT);
        const int cb = head * 16 + j * 8;
        float2 f0 = __half22float2(o0), f1 = __half22float2(o1);
        float2 f2 = __half22float2(o2), f3 = __half22float2(o3);
        union { float4 f; unsigned short u[8]; } pk;
        pk.u[0] = f2bf(f0.x * inv); pk.u[1] = f2bf(f0.y * inv);
        pk.u[2] = f2bf(f1.x * inv); pk.u[3] = f2bf(f1.y * inv);
        pk.u[4] = f2bf(f2.x * inv); pk.u[5] = f2bf(f2.y * inv);
        pk.u[6] = f2bf(f3.x * inv); pk.u[7] = f2bf(f3.y * inv);
        *(float4*)&aob[(size_t)pix * 64 + cb] = pk.f;
    }
}

// ---- k5: fused proj(64->256)+bias+residual -> cls(256->80), all bf16 MFMA ----
// grid 512 (b = blk&7, row = blk>>3), block 256 = 4 waves; wave = 16-px tile.
__global__ __launch_bounds__(256) void k5_mfma(
    const float* __restrict__ x, const float* __restrict__ bproj,
    const float* __restrict__ bcls, float* __restrict__ ws, float* __restrict__ out)
{
    __shared__ unsigned short tmp[64][264];   // bf16 [px][256 c] pad 8 -> 33.8 KB
    const int t = threadIdx.x;
    const int b = blockIdx.x & 7, row = blockIdx.x >> 3;
    const int wv = __builtin_amdgcn_readfirstlane(t >> 6);
    const int lane = t & 63, quad = lane >> 4, pxl = lane & 15;
    const int px = wv * 16 + pxl;
    const int pixcol = row * 64 + px;
    const size_t pix = (size_t)b * HW + pixcol;
    const unsigned short* aob = (const unsigned short*)(ws + OFF_AOT);
    const unsigned short* wpb = (const unsigned short*)(ws + OFF_WPT);
    const unsigned short* wcb = (const unsigned short*)(ws + OFF_WCT);

    union FB { float4 f; bf16x8 v; };
    FB bf0, bf1;
    bf0.f = *(const float4*)&aob[pix * 64 + quad * 8];
    bf1.f = *(const float4*)&aob[pix * 64 + 32 + quad * 8];

    // proj: 16 o-tiles of 16; k = 64 (2 MFMA)
    #pragma unroll 4
    for (int ot = 0; ot < 16; ++ot) {
        f32x4 acc = (f32x4){0.f, 0.f, 0.f, 0.f};
        FB a0, a1;
        const int om = ot * 16 + pxl;
        a0.f = *(const float4*)&wpb[om * 64 + quad * 8];
        a1.f = *(const float4*)&wpb[om * 64 + 32 + quad * 8];
        acc = __builtin_amdgcn_mfma_f32_16x16x32_bf16(a0.v, bf0.v, acc, 0, 0, 0);
        acc = __builtin_amdgcn_mfma_f32_16x16x32_bf16(a1.v, bf1.v, acc, 0, 0, 0);
        union { unsigned short u[4]; ushort2 s2[2]; } pk;
        #pragma unroll
        for (int r = 0; r < 4; ++r) {
            int o = ot * 16 + quad * 4 + r;
            float v = acc[r] + bproj[o] + x[(size_t)(b * DIM + o) * HW + pixcol];
            pk.u[r] = f2bf(v);
        }
        *(ushort4*)&tmp[px][ot * 16 + quad * 4] = *(ushort4*)pk.u;
    }
    __syncthreads();

    // cls: 5 oc-tiles of 16; k = 256 (8 chunks)
    f32x4 acc2[5];
    #pragma unroll
    for (int oc = 0; oc < 5; ++oc) acc2[oc] = (f32x4){0.f, 0.f, 0.f, 0.f};
    #pragma unroll
    for (int kc = 0; kc < 8; ++kc) {
        FB bb;
        bb.f = *(const float4*)&tmp[px][kc * 32 + quad * 8];
        #pragma unroll
        for (int oc = 0; oc < 5; ++oc) {
            FB aa;
            aa.f = *(const float4*)&wcb[(oc * 16 + pxl) * 256 + kc * 32 + quad * 8];
            acc2[oc] = __builtin_amdgcn_mfma_f32_16x16x32_bf16(aa.v, bb.v, acc2[oc], 0, 0, 0);
        }
    }
    #pragma unroll
    for (int oc = 0; oc < 5; ++oc) {
        #pragma unroll
        for (int r = 0; r < 4; ++r) {
            int o = oc * 16 + quad * 4 + r;
            out[(size_t)(b * NCLS + o) * HW + pixcol] = acc2[oc][r] + bcls[o];
        }
    }
}

extern "C" void kernel_launch(void* const* d_in, const int* in_sizes, int n_in,
                              void* d_out, int out_size, void* d_ws, size_t ws_size,
                              hipStream_t stream)
{
    const float* x     = (const float*)d_in[0];
    const float* off   = (const float*)d_in[1];
    const float* g1    = (const float*)d_in[2];
    const float* b1    = (const float*)d_in[3];
    const float* wqkv  = (const float*)d_in[4];
    const float* wdw   = (const float*)d_in[5];
    const float* g2    = (const float*)d_in[6];
    const float* b2    = (const float*)d_in[7];
    const float* woff  = (const float*)d_in[8];
    const float* boff  = (const float*)d_in[9];
    const float* rpb   = (const float*)d_in[10];
    const float* wproj = (const float*)d_in[11];
    const float* bproj = (const float*)d_in[12];
    const float* wcls  = (const float*)d_in[13];
    const float* bcls  = (const float*)d_in[14];
    float* ws  = (float*)d_ws;
    float* out = (float*)d_out;

    hipLaunchKernelGGL(k0_prep,     dim3(449),  dim3(256), 0, stream, wqkv, g1, b1, woff, wproj, wcls, ws);
    hipLaunchKernelGGL(k1_mfma,     dim3(512),  dim3(512), 0, stream, x, ws);
    hipLaunchKernelGGL(k2_off_feat, dim3(1024), dim3(256), 0, stream, wdw, g2, b2, ws);
    hipLaunchKernelGGL(k3_pred_off, dim3(1024), dim3(256), 0, stream, boff, off, ws);
    hipLaunchKernelGGL(k4_attn,     dim3(2048), dim3(256), 0, stream, rpb, ws);
    hipLaunchKernelGGL(k5_mfma,     dim3(512),  dim3(256), 0, stream, x, bproj, bcls, ws, out);
}